// Round 12
// baseline (204.941 us; speedup 1.0000x reference)
//
#include <hip/hip_runtime.h>
#include <hip/hip_bf16.h>

#define HDN 1024
#define NH  16
#define DH  64
#define NB  2
#define SQL 2048
#define MT  (NB*SQL)   // 4096

using bf16 = __hip_bfloat16;
typedef __attribute__((ext_vector_type(8))) short s16x8;
typedef __attribute__((ext_vector_type(4))) float f32x4;
typedef __attribute__((ext_vector_type(16))) float f32x16;
typedef unsigned int u32;

// 0.125 * log2(e): folds softmax scale AND exp->exp2 base change into Q projection
#define QSC 0.18033688011112042f

__device__ __forceinline__ void gload_lds16(const void* g, void* l) {
  __builtin_amdgcn_global_load_lds((const __attribute__((address_space(1))) void*)g,
                                   (__attribute__((address_space(3))) void*)l, 16, 0, 0);
}

__device__ __forceinline__ unsigned short bfb(float f) {
  union { __hip_bfloat16 h; unsigned short u; } c;
  c.h = __float2bfloat16(f);
  return c.u;
}

__device__ __forceinline__ u32 cvtpk(float lo, float hi) {
  u32 r;
  asm("v_cvt_pk_bf16_f32 %0, %1, %2" : "=v"(r) : "v"(lo), "v"(hi));
  return r;
}

// swaps a's upper 32 lanes with b's lower 32 lanes (v_permlane32_swap_b32)
__device__ __forceinline__ void pl32swap(u32& a, u32& b) {
  asm("v_permlane32_swap_b32 %0, %1" : "+v"(a), "+v"(b));
}

// ---------------- x: f32 -> bf16 ----------------
__global__ __launch_bounds__(256) void k_cvt_x(const float* __restrict__ x, bf16* __restrict__ xb) {
  int i = (blockIdx.x * 256 + threadIdx.x) * 8;
  float4 a = *(const float4*)(x + i);
  float4 b = *(const float4*)(x + i + 4);
  union { unsigned short u[8]; uint4 v; } o;
  o.u[0]=bfb(a.x); o.u[1]=bfb(a.y); o.u[2]=bfb(a.z); o.u[3]=bfb(a.w);
  o.u[4]=bfb(b.x); o.u[5]=bfb(b.y); o.u[6]=bfb(b.z); o.u[7]=bfb(b.w);
  *(uint4*)((unsigned short*)xb + i) = o.v;
}

// ---------------- W [in][out] f32 -> W^T [out][in] bf16 ----------------
__global__ __launch_bounds__(256) void k_trw(const float* __restrict__ Wq, const float* __restrict__ Wk,
                                             const float* __restrict__ Wv, const float* __restrict__ Wo,
                                             bf16* __restrict__ WqkvT, bf16* __restrict__ WoT) {
  __shared__ float tile[64][65];
  int z = blockIdx.z;
  const float* W = (z==0)?Wq:(z==1)?Wk:(z==2)?Wv:Wo;
  bf16* Wt = (z<3) ? (WqkvT + (size_t)z*HDN*HDN) : WoT;
  int r0 = blockIdx.y*64, c0 = blockIdx.x*64;
  int t = threadIdx.x, tr = t>>4, tc = (t&15)*4;
  #pragma unroll
  for (int p=0;p<4;p++){
    int r = p*16+tr;
    float4 v = *(const float4*)(W + (size_t)(r0+r)*HDN + c0 + tc);
    tile[r][tc]=v.x; tile[r][tc+1]=v.y; tile[r][tc+2]=v.z; tile[r][tc+3]=v.w;
  }
  __syncthreads();
  #pragma unroll
  for (int p=0;p<4;p++){
    int o = p*16+tr;
    union { unsigned short u[4]; ushort4 v; } pk;
    #pragma unroll
    for (int j=0;j<4;j++) pk.u[j] = bfb(tile[tc+j][o]);
    *(ushort4*)((unsigned short*)Wt + (size_t)(c0+o)*HDN + r0 + tc) = pk.v;
  }
}

// ---------------- GEMM: C[m][n] = A[m][k] * B^T[n][k], 128x128x64 ----------------
// MODE 0: N=3072, epilogue -> Q*QSC [b,h,s,d], K [b,h,s,d] (both via LDS bounce,
//         coalesced 16B stores), V^T [b,h,d,s] (LDS transpose bounce), bf16 + bias
// MODE 1: N=1024, epilogue -> out f32 + bias
// Both: XCD-aware bijective block swizzle; 3 blocks/CU via __launch_bounds__(256,3).
template<int MODE>
__global__ __launch_bounds__(256,3) void k_gemm(
    const bf16* __restrict__ A, const bf16* __restrict__ B,
    const float* __restrict__ b0, const float* __restrict__ b1, const float* __restrict__ b2,
    bf16* __restrict__ oq, bf16* __restrict__ ok, bf16* __restrict__ ovt, float* __restrict__ oo) {
  constexpr int KD = 1024;
  __shared__ __align__(16) char smem[34816];     // main loop: As 16K | Bs 16K ; epilogue: [128][136] bf16 tile
  bf16* As = (bf16*)smem;
  bf16* Bs = (bf16*)(smem + 16384);
  int tid = threadIdx.x, lane = tid&63, wave = tid>>6;
  int g = lane>>4, lr = lane&15;

  // XCD swizzle: dispatch slot lin runs on XCD lin%8; give each XCD a contiguous tile range
  int lin = blockIdx.y * gridDim.x + blockIdx.x;
  int nwg = gridDim.x * gridDim.y;
  int wg  = (lin & 7) * (nwg >> 3) + (lin >> 3);
  int bx  = wg % gridDim.x, by = wg / gridDim.x;

  int m0 = by*128, n0 = bx*128;
  int wm = (wave>>1)*64, wn = (wave&1)*64;
  f32x4 acc[4][4] = {};
  for (int k0=0; k0<KD; k0+=64) {
    #pragma unroll
    for (int i=0;i<4;i++){
      int seg = wave*4+i;
      int flat = seg*64 + lane;
      int row = flat>>3, ch = flat&7;
      gload_lds16(A + (size_t)(m0+row)*KD + k0 + ch*8, (char*)As + seg*1024);
      gload_lds16(B + (size_t)(n0+row)*KD + k0 + ch*8, (char*)Bs + seg*1024);
    }
    __syncthreads();
    #pragma unroll
    for (int kk=0;kk<2;kk++){
      s16x8 af[4], bfg[4];
      #pragma unroll
      for (int mi=0;mi<4;mi++)
        af[mi] = *(const s16x8*)((const char*)As + (wm+mi*16+lr)*128 + kk*64 + g*16);
      #pragma unroll
      for (int ni=0;ni<4;ni++)
        bfg[ni] = *(const s16x8*)((const char*)Bs + (wn+ni*16+lr)*128 + kk*64 + g*16);
      #pragma unroll
      for (int mi=0;mi<4;mi++)
        #pragma unroll
        for (int ni=0;ni<4;ni++)
          acc[mi][ni] = __builtin_amdgcn_mfma_f32_16x16x32_bf16(af[mi], bfg[ni], acc[mi][ni], 0,0,0);
    }
    __syncthreads();
  }
  if (MODE == 0) {
    int proj = n0 >> 10;                 // block's 128 cols lie in one projection
    if (proj < 2) {
      // Q/K: bounce through LDS [m 128][n 128 bf16, stride 272B] -> coalesced 16B stores
      const float* bias = (proj==0)?b0:b1;
      bf16* oqk = (proj==0)?oq:ok;
      float qscale = (proj==0) ? QSC : 1.0f;
      #pragma unroll
      for (int ni=0;ni<4;ni++){
        int nl = wn + ni*16 + lr;
        float bv = bias[(n0&1023) + nl];
        #pragma unroll
        for (int mi=0;mi<4;mi++)
          #pragma unroll
          for (int r=0;r<4;r++){
            int ml = wm + mi*16 + g*4 + r;
            *(unsigned short*)(smem + ml*272 + nl*2) = bfb((acc[mi][ni][r] + bv) * qscale);
          }
      }
      __syncthreads();
      int bb = m0 >> 11;
      int h0 = (n0 & 1023) >> 6;
      #pragma unroll
      for (int it=0; it<8; ++it){
        int flat = it*256 + tid;
        int row = flat>>4, chk = flat&15;
        s16x8 val = *(const s16x8*)(smem + row*272 + chk*16);
        int s = (m0 & 2047) + row;
        int hh = h0 + (chk>>3), dd = (chk&7)*8;
        *(s16x8*)(oqk + ((size_t)((bb*NH+hh)*SQL + s))*DH + dd) = val;
      }
    } else {
      // V^T: transpose through LDS, then 16B coalesced stores.
      // vt tile: [128 n][136 m] bf16, row stride 272B (16B aligned).
      #pragma unroll
      for (int ni=0;ni<4;ni++){
        int nl = wn + ni*16 + lr;
        float bv = b2[(n0 & 1023) + nl];
        #pragma unroll
        for (int mi=0;mi<4;mi++){
          #pragma unroll
          for (int rp=0; rp<4; rp+=2){
            int ml = wm + mi*16 + g*4 + rp;
            u32 pkd = (u32)bfb(acc[mi][ni][rp] + bv) | ((u32)bfb(acc[mi][ni][rp+1] + bv) << 16);
            *(u32*)(smem + nl*272 + ml*2) = pkd;
          }
        }
      }
      __syncthreads();
      int bb = m0 >> 11;
      #pragma unroll
      for (int it=0; it<8; ++it){
        int flat = it*256 + tid;
        int row = flat>>4, chk = flat&15;
        s16x8 val = *(const s16x8*)(smem + row*272 + chk*16);
        int wi = (n0 & 1023) + row;
        int hh = wi>>6, dd = wi&63;
        int ss = (m0 & 2047) + chk*8;
        *(s16x8*)(ovt + ((size_t)((bb*NH+hh)*DH + dd))*SQL + ss) = val;
      }
    }
  } else {
    #pragma unroll
    for (int ni=0;ni<4;ni++){
      int n = n0 + wn + ni*16 + lr;
      float bv = b0[n];
      #pragma unroll
      for (int mi=0;mi<4;mi++)
        #pragma unroll
        for (int r=0;r<4;r++){
          int m = m0 + wm + mi*16 + g*4 + r;
          oo[(size_t)m*HDN + n] = acc[mi][ni][r] + bv;
        }
    }
  }
}

// ---------------- flash attention: 2 q-sub-tiles per wave, K-split, NO-MAX softmax ----------------
// 256 thr = 4 waves = 2 kc (key chunks of 1024) x 2 qw. Each wave owns 64 q-rows as two
// 32-row sub-tiles (A: +0, B: +32). K/V frags are the shared MFMA A-operand, so one frag
// read feeds BOTH sub-tiles -> LDS reads, staging, and barriers per q-row are HALVED vs
// one-tile waves. l = row-sum of P computed as VALU by-product of the exp2 loop.
// LDS 64KB/block -> 2 blocks/CU. Grid 512 = 32 bh x 16 qt; bh=blk&31 pins head to XCD.
__global__ __launch_bounds__(256,2) void k_attn(
    const bf16* __restrict__ Q, const bf16* __restrict__ K, const bf16* __restrict__ Vt,
    bf16* __restrict__ ctx) {
  __shared__ __align__(16) char sm[2][2][16384];   // [kc][dbuf][K 8KB | V 8KB], XOR-swizzled
  int bh = blockIdx.x & 31, qt = blockIdx.x >> 5;
  int b = bh >> 4, h = bh & 15;
  int tid = threadIdx.x;
  int kc = tid >> 7, tl = tid & 127;               // key chunk, thread-in-half (128 thr)
  int qw = tl >> 6;                                // wave within half
  int lane = tid & 63;
  int cl = lane & 31, hi = lane >> 5;
  const char* Kc = (const char*)(K  + (size_t)bh*SQL*DH);
  const char* Vc = (const char*)(Vt + (size_t)bh*DH*SQL);
  const bf16* Qb = Q + (size_t)bh*SQL*DH;

  // staging source offsets (inverse-swizzled global; LDS dest linear).
  // pass p covers tile rows r = (tl>>3) + p*16; col c = ((tl&7)*16) ^ ((r&7)<<4)
  int r8 = tl >> 3;
  int cS = ((tl & 7) * 16) ^ ((r8 & 7) << 4);
  size_t kS = (size_t)r8*128  + cS;     // K rows: 128B stride
  size_t vS = (size_t)r8*4096 + cS;     // Vt rows: 4096B stride

  // swizzled LDS read column offsets
  int swz = (cl&7)<<4;
  int cswz0 = (0*32 + hi*16) ^ swz;
  int cswz1 = (1*32 + hi*16) ^ swz;
  int cswz2 = (2*32 + hi*16) ^ swz;
  int cswz3 = (3*32 + hi*16) ^ swz;
  int rbase0 = cl*128;
  int rbase1 = (32+cl)*128;

  // Q fragments for the wave's two 32-row sub-tiles (loop-invariant)
  int q0 = qt*128 + qw*64;
  s16x8 qfA[4], qfB[4];
  #pragma unroll
  for (int ds=0; ds<4; ++ds){
    qfA[ds] = *(const s16x8*)((const char*)Qb + (size_t)(q0+cl)*128    + ds*32 + hi*16);
    qfB[ds] = *(const s16x8*)((const char*)Qb + (size_t)(q0+32+cl)*128 + ds*32 + hi*16);
  }

  f32x16 caA0 = {}, caA1 = {}, caB0 = {}, caB1 = {};
  float lrA = 0.f, lrB = 0.f;

  auto STAGE = [&](int bb, int t){
    int k0 = kc*1024 + t*64;
    char* bK = &sm[kc][bb][0]; char* bV = bK + 8192;
    const char* kp = Kc + (size_t)k0*128 + kS;
    const char* vp = Vc + (size_t)k0*2   + vS;
    #pragma unroll
    for (int p=0; p<4; ++p){
      gload_lds16(kp + p*2048,          bK + qw*1024 + p*2048);
      gload_lds16(vp + (size_t)p*65536, bV + qw*1024 + p*2048);
    }
  };

  STAGE(0, 0);
  __syncthreads();

  for (int t=0; t<16; ++t){
    int cur = t & 1;
    if (t < 15) STAGE(cur^1, t+1);
    const char* bK = &sm[kc][cur][0];
    const char* bV = bK + 8192;

    // ---- QK^T for both sub-tiles off shared K-frags (log2 domain) ----
    f32x16 sA0 = {}, sA1 = {}, sB0 = {}, sB1 = {};
    __builtin_amdgcn_s_setprio(1);
    {
      s16x8 k00 = *(const s16x8*)(bK + rbase0 + cswz0);
      s16x8 k10 = *(const s16x8*)(bK + rbase1 + cswz0);
      sA0 = __builtin_amdgcn_mfma_f32_32x32x16_bf16(k00, qfA[0], sA0, 0,0,0);
      sA1 = __builtin_amdgcn_mfma_f32_32x32x16_bf16(k10, qfA[0], sA1, 0,0,0);
      sB0 = __builtin_amdgcn_mfma_f32_32x32x16_bf16(k00, qfB[0], sB0, 0,0,0);
      sB1 = __builtin_amdgcn_mfma_f32_32x32x16_bf16(k10, qfB[0], sB1, 0,0,0);
      s16x8 k01 = *(const s16x8*)(bK + rbase0 + cswz1);
      s16x8 k11 = *(const s16x8*)(bK + rbase1 + cswz1);
      sA0 = __builtin_amdgcn_mfma_f32_32x32x16_bf16(k01, qfA[1], sA0, 0,0,0);
      sA1 = __builtin_amdgcn_mfma_f32_32x32x16_bf16(k11, qfA[1], sA1, 0,0,0);
      sB0 = __builtin_amdgcn_mfma_f32_32x32x16_bf16(k01, qfB[1], sB0, 0,0,0);
      sB1 = __builtin_amdgcn_mfma_f32_32x32x16_bf16(k11, qfB[1], sB1, 0,0,0);
      s16x8 k02 = *(const s16x8*)(bK + rbase0 + cswz2);
      s16x8 k12 = *(const s16x8*)(bK + rbase1 + cswz2);
      sA0 = __builtin_amdgcn_mfma_f32_32x32x16_bf16(k02, qfA[2], sA0, 0,0,0);
      sA1 = __builtin_amdgcn_mfma_f32_32x32x16_bf16(k12, qfA[2], sA1, 0,0,0);
      sB0 = __builtin_amdgcn_mfma_f32_32x32x16_bf16(k02, qfB[2], sB0, 0,0,0);
      sB1 = __builtin_amdgcn_mfma_f32_32x32x16_bf16(k12, qfB[2], sB1, 0,0,0);
      s16x8 k03 = *(const s16x8*)(bK + rbase0 + cswz3);
      s16x8 k13 = *(const s16x8*)(bK + rbase1 + cswz3);
      sA0 = __builtin_amdgcn_mfma_f32_32x32x16_bf16(k03, qfA[3], sA0, 0,0,0);
      sA1 = __builtin_amdgcn_mfma_f32_32x32x16_bf16(k13, qfA[3], sA1, 0,0,0);
      sB0 = __builtin_amdgcn_mfma_f32_32x32x16_bf16(k03, qfB[3], sB0, 0,0,0);
      sB1 = __builtin_amdgcn_mfma_f32_32x32x16_bf16(k13, qfB[3], sB1, 0,0,0);
    }
    __builtin_amdgcn_s_setprio(0);

    // ---- P = exp2(S); l accumulated on VALU; pack to bf16 B-fragments ----
    s16x8 pfA[4], pfB[4];
    #pragma unroll
    for (int st=0; st<2; ++st){
      const f32x16& t0 = st ? sB0 : sA0;
      const f32x16& t1 = st ? sB1 : sA1;
      float ls = 0.f;
      s16x8* pf = st ? pfB : pfA;
      #pragma unroll
      for (int kb=0; kb<2; ++kb){
        float e[16];
        #pragma unroll
        for (int i=0;i<16;i++){ e[i] = exp2f(kb ? t1[i] : t0[i]); ls += e[i]; }
        u32 w00=cvtpk(e[0],e[1]),   w01=cvtpk(e[2],e[3]);
        u32 w10=cvtpk(e[4],e[5]),   w11=cvtpk(e[6],e[7]);
        u32 w20=cvtpk(e[8],e[9]),   w21=cvtpk(e[10],e[11]);
        u32 w30=cvtpk(e[12],e[13]), w31=cvtpk(e[14],e[15]);
        pl32swap(w00, w10);
        pl32swap(w01, w11);
        pl32swap(w20, w30);
        pl32swap(w21, w31);
        union { u32 u[4]; s16x8 v; } Au, Bu;
        Au.u[0]=w00; Au.u[1]=w01; Au.u[2]=w10; Au.u[3]=w11;
        Bu.u[0]=w20; Bu.u[1]=w21; Bu.u[2]=w30; Bu.u[3]=w31;
        pf[kb*2]   = Au.v;
        pf[kb*2+1] = Bu.v;
      }
      if (st) lrB += ls; else lrA += ls;
    }

    // ---- PV for both sub-tiles off shared V-frags ----
    __builtin_amdgcn_s_setprio(1);
    {
      s16x8 v00 = *(const s16x8*)(bV + rbase0 + cswz0);
      s16x8 v10 = *(const s16x8*)(bV + rbase1 + cswz0);
      caA0 = __builtin_amdgcn_mfma_f32_32x32x16_bf16(v00, pfA[0], caA0, 0,0,0);
      caA1 = __builtin_amdgcn_mfma_f32_32x32x16_bf16(v10, pfA[0], caA1, 0,0,0);
      caB0 = __builtin_amdgcn_mfma_f32_32x32x16_bf16(v00, pfB[0], caB0, 0,0,0);
      caB1 = __builtin_amdgcn_mfma_f32_32x32x16_bf16(v10, pfB[0], caB1, 0,0,0);
      s16x8 v01 = *(const s16x8*)(bV + rbase0 + cswz1);
      s16x8 v11 = *(const s16x8*)(bV + rbase1 + cswz1);
      caA0 = __builtin_amdgcn_mfma_f32_32x32x16_bf16(v01, pfA[1], caA0, 0,0,0);
      caA1 = __builtin_amdgcn_mfma_f32_32x32x16_bf16(v11, pfA[1], caA1, 0,0,0);
      caB0 = __builtin_amdgcn_mfma_f32_32x32x16_bf16(v01, pfB[1], caB0, 0,0,0);
      caB1 = __builtin_amdgcn_mfma_f32_32x32x16_bf16(v11, pfB[1], caB1, 0,0,0);
      s16x8 v02 = *(const s16x8*)(bV + rbase0 + cswz2);
      s16x8 v12 = *(const s16x8*)(bV + rbase1 + cswz2);
      caA0 = __builtin_amdgcn_mfma_f32_32x32x16_bf16(v02, pfA[2], caA0, 0,0,0);
      caA1 = __builtin_amdgcn_mfma_f32_32x32x16_bf16(v12, pfA[2], caA1, 0,0,0);
      caB0 = __builtin_amdgcn_mfma_f32_32x32x16_bf16(v02, pfB[2], caB0, 0,0,0);
      caB1 = __builtin_amdgcn_mfma_f32_32x32x16_bf16(v12, pfB[2], caB1, 0,0,0);
      s16x8 v03 = *(const s16x8*)(bV + rbase0 + cswz3);
      s16x8 v13 = *(const s16x8*)(bV + rbase1 + cswz3);
      caA0 = __builtin_amdgcn_mfma_f32_32x32x16_bf16(v03, pfA[3], caA0, 0,0,0);
      caA1 = __builtin_amdgcn_mfma_f32_32x32x16_bf16(v13, pfA[3], caA1, 0,0,0);
      caB0 = __builtin_amdgcn_mfma_f32_32x32x16_bf16(v03, pfB[3], caB0, 0,0,0);
      caB1 = __builtin_amdgcn_mfma_f32_32x32x16_bf16(v13, pfB[3], caB1, 0,0,0);
    }
    __builtin_amdgcn_s_setprio(0);
    __syncthreads();
  }

  // ---- merge the two k-chunks through LDS: O = (O0+O1)/(l0+l1) ----
  lrA += __shfl_xor(lrA, 32, 64);       // cross-half l merge
  lrB += __shfl_xor(lrB, 32, 64);

  char*  base = &sm[0][0][0];
  float* lb   = (float*)(base + 16384);   // [4 su][32] f32
  float* o2b  = (float*)(base + 32768);   // [4 su][64 d][32 q] f32 = 32KB
  char*  cb   = base;                     // ctx bounce, 16KB

  __syncthreads();
  if (kc == 1) {
    if (!hi) { lb[(qw*2+0)*32+cl] = lrA; lb[(qw*2+1)*32+cl] = lrB; }
    #pragma unroll
    for (int st=0; st<2; ++st){
      int su = qw*2 + st;
      #pragma unroll
      for (int db=0; db<2; ++db)
        #pragma unroll
        for (int r=0; r<16; ++r){
          int d = db*32 + (r&3) + 8*(r>>2) + 4*hi;
          float v = st ? (db ? caB1[r] : caB0[r]) : (db ? caA1[r] : caA0[r]);
          o2b[su*2048 + d*32 + cl] = v;
        }
    }
  }
  __syncthreads();
  if (kc == 0) {
    #pragma unroll
    for (int st=0; st<2; ++st){
      int su = qw*2 + st;
      float lr = st ? lrB : lrA;
      float inv = 1.f / (lr + lb[su*32+cl]);
      int row = su*32 + cl;
      int rswz = (row&7)<<4;
      #pragma unroll
      for (int db=0; db<2; ++db){
        #pragma unroll
        for (int r=0; r<16; r+=2){
          int d = db*32 + (r&3) + 8*(r>>2) + 4*hi;
          float sa = st ? (db ? caB1[r]   : caB0[r])   : (db ? caA1[r]   : caA0[r]);
          float sb = st ? (db ? caB1[r+1] : caB0[r+1]) : (db ? caA1[r+1] : caA0[r+1]);
          float va = (sa + o2b[su*2048 + d*32     + cl]) * inv;
          float vb = (sb + o2b[su*2048 + (d+1)*32 + cl]) * inv;
          *(u32*)(cb + row*128 + ((d*2) ^ rswz)) = cvtpk(va, vb);
        }
      }
    }
  }
  __syncthreads();
  if (kc == 0) {
    #pragma unroll
    for (int i=0;i<8;i++){
      int flat = i*128 + tl, orow = flat>>3, ch = flat&7;
      s16x8 cv = *(const s16x8*)(cb + orow*128 + ((ch*16) ^ ((orow&7)<<4)));
      *(s16x8*)(ctx + (size_t)(b*SQL + qt*128 + orow)*HDN + h*DH + ch*8) = cv;
    }
  }
}

extern "C" void kernel_launch(void* const* d_in, const int* in_sizes, int n_in,
                              void* d_out, int out_size, void* d_ws, size_t ws_size,
                              hipStream_t stream) {
  const float* x  = (const float*)d_in[0];
  const float* Wq = (const float*)d_in[1];
  const float* bq = (const float*)d_in[2];
  const float* Wk = (const float*)d_in[3];
  const float* bk = (const float*)d_in[4];
  const float* Wv = (const float*)d_in[5];
  const float* bv = (const float*)d_in[6];
  const float* Wo = (const float*)d_in[7];
  const float* bo = (const float*)d_in[8];
  char* ws = (char*)d_ws;
  bf16* xb    = (bf16*)(ws);                         // 8 MB   x bf16 [4096][1024]
  bf16* WqkvT = (bf16*)(ws + ((size_t)8<<20));       // 6 MB   [3072][1024]
  bf16* WoT   = (bf16*)(ws + ((size_t)14<<20));      // 2 MB   [1024][1024]
  bf16* Qg    = (bf16*)(ws + ((size_t)16<<20));      // 8 MB   [b,h,s,d] (pre-scaled by QSC)
  bf16* Kg    = (bf16*)(ws + ((size_t)24<<20));      // 8 MB   [b,h,s,d]
  bf16* Vtg   = (bf16*)(ws + ((size_t)32<<20));      // 8 MB   [b,h,d,s]
  bf16* Ctx   = (bf16*)(ws + ((size_t)40<<20));      // 8 MB   [b,s,h*d]
  float* out  = (float*)d_out;

  k_cvt_x<<<2048, 256, 0, stream>>>(x, xb);
  k_trw<<<dim3(16,16,4), 256, 0, stream>>>(Wq, Wk, Wv, Wo, WqkvT, WoT);
  k_gemm<0><<<dim3(24,32), 256, 0, stream>>>(xb, WqkvT, bq, bk, bv, Qg, Kg, Vtg, nullptr);
  k_attn<<<512, 256, 0, stream>>>(Qg, Kg, Vtg, Ctx);
  k_gemm<1><<<dim3(8,32), 256, 0, stream>>>(Ctx, WoT, bo, nullptr, nullptr,
                                            nullptr, nullptr, nullptr, out);
}